// Round 17
// baseline (317.180 us; speedup 1.0000x reference)
//
#include <hip/hip_runtime.h>

#define NREL 8
#define CH   128                 // IN_CH == HID == 128
#define YW   1152                // y row width: 8 rels + root, each 128
#define YWD  (YW / 2)            // y row width in dwords (576)
#define NCB2 18                  // 64-col chunks in ygemm

#define SCAN_ITEMS   16
#define SCAN_THREADS 256
#define SCAN_CHUNK   (SCAN_ITEMS * SCAN_THREADS)   // 4096
#define SCAN_SHIFT   12

typedef short  short8v __attribute__((ext_vector_type(8)));
typedef float  f32x4   __attribute__((ext_vector_type(4)));

__device__ __forceinline__ unsigned short f2bf(float f) {
    union { float f; unsigned u; } v; v.f = f;
    return (unsigned short)((v.u + 0x7FFFu + ((v.u >> 16) & 1u)) >> 16);
}
__device__ __forceinline__ float lof(unsigned u) {
    union { unsigned u; float f; } v; v.u = u << 16; return v.f;
}
__device__ __forceinline__ float hif(unsigned u) {
    union { unsigned u; float f; } v; v.u = u & 0xFFFF0000u; return v.f;
}
__device__ __forceinline__ void gload_lds16(const void* g, void* l) {
    __builtin_amdgcn_global_load_lds(
        (const __attribute__((address_space(1))) unsigned int*)g,
        (__attribute__((address_space(3))) unsigned int*)l, 16, 0, 0);
}

// ---------------------------------------------------------------------------
// 0. Bt2[rc][k] = bf16( Wcat[k][rc] ); rc = r*128+c
// ---------------------------------------------------------------------------
__global__ __launch_bounds__(256) void bt2_kernel(
    const float* __restrict__ W, const float* __restrict__ root,
    unsigned short* __restrict__ Bt2)
{
    int idx = blockIdx.x * blockDim.x + threadIdx.x;   // rc*128 + k
    if (idx >= YW * CH) return;
    int rc = idx >> 7, k = idx & 127;
    int r = rc >> 7, c = rc & 127;
    float v = (r < NREL) ? W[(size_t)(r * CH + k) * CH + c]
                         : root[(size_t)k * CH + c];
    Bt2[idx] = f2bf(v);
}

// ---------------------------------------------------------------------------
// 1. hist + rank: rank[e] = old count of segment (dst*8+et), coalesced write.
// ---------------------------------------------------------------------------
__global__ __launch_bounds__(256) void hist_rank_kernel(
    const int* __restrict__ dst, const int* __restrict__ et,
    int* __restrict__ hist, int* __restrict__ rank, int E)
{
    int e = blockIdx.x * blockDim.x + threadIdx.x;
    if (e < E) rank[e] = atomicAdd(&hist[dst[e] * NREL + et[e]], 1);
}

// ---------------------------------------------------------------------------
// 2a/2b. two-level exclusive scan over S segments -> pad_offs[i] = seg start
// ---------------------------------------------------------------------------
__global__ __launch_bounds__(SCAN_THREADS) void scan1_kernel(
    const int* __restrict__ hist, int* __restrict__ pad_offs,
    int* __restrict__ partials, int S)
{
    __shared__ int lds[SCAN_THREADS];
    int t = threadIdx.x;
    int base = blockIdx.x * SCAN_CHUNK + t * SCAN_ITEMS;
    int v[SCAN_ITEMS];
    int s = 0;
#pragma unroll
    for (int j = 0; j < SCAN_ITEMS; j++) {
        int idx = base + j;
        int h = (idx < S) ? hist[idx] : 0;
        v[j] = s; s += h;
    }
    int run = s;
    lds[t] = run; __syncthreads();
    for (int off = 1; off < SCAN_THREADS; off <<= 1) {
        int y = (t >= off) ? lds[t - off] : 0;
        __syncthreads();
        run += y; lds[t] = run; __syncthreads();
    }
    int tb = run - s;
    if (t == SCAN_THREADS - 1) partials[blockIdx.x] = run;
#pragma unroll
    for (int j = 0; j < SCAN_ITEMS; j++) {
        int idx = base + j;
        if (idx < S) pad_offs[idx] = tb + v[j];
    }
}

__global__ __launch_bounds__(SCAN_THREADS) void scan2_kernel(
    int* __restrict__ partials, int NB)
{
    __shared__ int lds[SCAN_THREADS];
    int t = threadIdx.x;
    int s = (t < NB) ? partials[t] : 0;
    int run = s;
    lds[t] = run; __syncthreads();
    for (int off = 1; off < SCAN_THREADS; off <<= 1) {
        int y = (t >= off) ? lds[t - off] : 0;
        __syncthreads();
        run += y; lds[t] = run; __syncthreads();
    }
    if (t < NB) partials[t] = run - s;
}

// ---------------------------------------------------------------------------
// 2c. pad_offs -> absolute; sentinel pad_offs[S] = E
// ---------------------------------------------------------------------------
__global__ __launch_bounds__(256) void finalize_kernel(
    int* __restrict__ pad_offs, const int* __restrict__ partials, int S, int E)
{
    int i = blockIdx.x * blockDim.x + threadIdx.x;
    if (i < S)       pad_offs[i] += partials[i >> SCAN_SHIFT];
    else if (i == S) pad_offs[i] = E;
}

// ---------------------------------------------------------------------------
// 4. FUSED ygemm + scatter-only fill. R11 base + SWAPPED-OPERAND MFMA:
//    mfma(b, a, acc) computes the transposed tile, so lane r15 = x-row and
//    kg*4+reg = 4 consecutive y-cols -> epilogue is ONE 8B store per mr
//    (4x fewer store insts / line-touches). Numerically identical.
// ---------------------------------------------------------------------------
__global__ __launch_bounds__(512, 6) void ygemm_fill_kernel(
    const float* __restrict__ x,
    const unsigned short* __restrict__ Bt2,   // [1152][128]
    unsigned short* __restrict__ y,           // [N][1152]
    int N,
    const int* __restrict__ src, const int* __restrict__ dst,
    const int* __restrict__ et, const int* __restrict__ rank,
    const int* __restrict__ pad_offs,
    int* __restrict__ perm, int E, int epb)
{
    __shared__ __align__(16) unsigned short As[128 * 128];  // 32 KB
    __shared__ __align__(16) unsigned short Bs[64 * 128];   // 16 KB

    int tid  = threadIdx.x;
    int lane = tid & 63;
    int wid  = tid >> 6;
    int wm   = wid >> 2;       // 0..1 -> 64-row half
    int wn   = wid & 3;        // 0..3 -> 16-col slice
    int r15  = lane & 15;
    int kg   = lane >> 4;      // 0..3
    int n0   = blockIdx.x * 128;

    // ---- fill prologue: compute positions (no atomics) ----
    int eb   = blockIdx.x * epb;
    int elim = eb + epb; if (elim > E) elim = E;
    int p0 = -1, p1 = -1, p2 = -1, p3 = -1;
    int v0 = 0, v1 = 0, v2 = 0, v3 = 0;
    {
        int e0 = eb + tid;
        int e1 = e0 + 512, e2 = e1 + 512, e3 = e2 + 512;
        if (e0 < elim) { int t0 = et[e0]; v0 = (src[e0] << 3) | t0;
                         p0 = pad_offs[dst[e0] * NREL + t0] + rank[e0]; }
        if (e1 < elim) { int t1 = et[e1]; v1 = (src[e1] << 3) | t1;
                         p1 = pad_offs[dst[e1] * NREL + t1] + rank[e1]; }
        if (e2 < elim) { int t2 = et[e2]; v2 = (src[e2] << 3) | t2;
                         p2 = pad_offs[dst[e2] * NREL + t2] + rank[e2]; }
        if (e3 < elim) { int t3 = et[e3]; v3 = (src[e3] << 3) | t3;
                         p3 = pad_offs[dst[e3] * NREL + t3] + rank[e3]; }
    }

    // ---- stage A once ----
    {
        int row = tid >> 2;
        int kq  = tid & 3;
        int gn  = n0 + row; if (gn >= N) gn = N - 1;
        const float* xp = x + (size_t)gn * CH + kq * 32;
#pragma unroll
        for (int s8 = 0; s8 < 4; ++s8) {
            float4 f0 = *(const float4*)(xp + s8 * 8);
            float4 f1 = *(const float4*)(xp + s8 * 8 + 4);
            uint4 v;
            v.x = f2bf(f0.x) | ((unsigned)f2bf(f0.y) << 16);
            v.y = f2bf(f0.z) | ((unsigned)f2bf(f0.w) << 16);
            v.z = f2bf(f1.x) | ((unsigned)f2bf(f1.y) << 16);
            v.w = f2bf(f1.z) | ((unsigned)f2bf(f1.w) << 16);
            int slot = kq * 4 + s8;
            int phys = slot ^ (row & 15);
            *(uint4*)&As[row * 128 + phys * 8] = v;
        }
    }

    for (int cb = 0; cb < NCB2; ++cb) {
        // ---- stage Bs: 64 cols x 128 k (16 x 1KB chunks, 2 per wave) ----
#pragma unroll
        for (int i = 0; i < 2; ++i) {
            int chunk = wid * 2 + i;              // 0..15
            int col   = chunk * 4 + (lane >> 4);  // 0..63
            int slot  = (lane & 15) ^ (col & 15);
            const char* srcp = (const char*)(Bt2 + (size_t)(cb * 64 + col) * CH + slot * 8);
            gload_lds16(srcp, &Bs[chunk * 512]);
        }
        __syncthreads();

        // ---- spread perm scatter: one store per early iteration ----
        if      (cb == 1) { if (p0 >= 0) perm[p0] = v0; }
        else if (cb == 2) { if (p1 >= 0) perm[p1] = v1; }
        else if (cb == 3) { if (p2 >= 0) perm[p2] = v2; }
        else if (cb == 4) { if (p3 >= 0) perm[p3] = v3; }

        f32x4 acc[4];
#pragma unroll
        for (int i = 0; i < 4; i++) acc[i] = f32x4{0.f, 0.f, 0.f, 0.f};

#pragma unroll
        for (int ks = 0; ks < 4; ++ks) {
            short8v a[4], b;
#pragma unroll
            for (int mr = 0; mr < 4; ++mr) {
                int row  = wm * 64 + mr * 16 + r15;
                int phys = (ks * 4 + kg) ^ (row & 15);
                a[mr] = *(const short8v*)&As[row * 128 + phys * 8];
            }
            {
                int col  = wn * 16 + r15;
                int phys = (ks * 4 + kg) ^ (col & 15);
                b = *(const short8v*)&Bs[col * 128 + phys * 8];
            }
            // SWAPPED operands: D = B_tile^T-style -> lane r15 = x-row,
            // kg*4+reg = y-col. Same products, transposed output layout.
#pragma unroll
            for (int mr = 0; mr < 4; ++mr)
                acc[mr] = __builtin_amdgcn_mfma_f32_16x16x32_bf16(
                    b, a[mr], acc[mr], 0, 0, 0);
        }

        // ---- epilogue: lane holds row = ...+r15, cols kg*4+0..3 ----
        {
            int gc = cb * 64 + wn * 16 + kg * 4;
#pragma unroll
            for (int mr = 0; mr < 4; ++mr) {
                int gr = n0 + wm * 64 + mr * 16 + r15;
                if (gr >= N) continue;
                uint2 o;
                o.x = f2bf(acc[mr][0]) | ((unsigned)f2bf(acc[mr][1]) << 16);
                o.y = f2bf(acc[mr][2]) | ((unsigned)f2bf(acc[mr][3]) << 16);
                *(uint2*)&y[(size_t)gr * YW + gc] = o;
            }
        }
        __syncthreads();
    }
}

// ---------------------------------------------------------------------------
// 5. gather (R11 v1): out[n] = relu( sum_e w_e * y[(pv+(pv>>3))*128..]
//    + y_root + bias ). One wave per node; unroll-16 row loads.
// ---------------------------------------------------------------------------
__global__ __launch_bounds__(256) void gather_kernel(
    const unsigned short* __restrict__ y,
    const int* __restrict__ perm,
    const int* __restrict__ pad_offs,
    const int* __restrict__ hist,
    const float* __restrict__ bias,
    float* __restrict__ out, int N)
{
    int wid  = threadIdx.x >> 6;
    int lane = threadIdx.x & 63;
    int n    = blockIdx.x * 4 + wid;
    if (n >= N) return;

    int beg = pad_offs[n * NREL];
    int end = pad_offs[n * NREL + NREL];

    int4 h0 = *(const int4*)(hist + (size_t)n * NREL);
    int4 h1 = *(const int4*)(hist + (size_t)n * NREL + 4);
    float iw0 = 1.0f / (float)max(h0.x, 1);
    float iw1 = 1.0f / (float)max(h0.y, 1);
    float iw2 = 1.0f / (float)max(h0.z, 1);
    float iw3 = 1.0f / (float)max(h0.w, 1);
    float iw4 = 1.0f / (float)max(h1.x, 1);
    float iw5 = 1.0f / (float)max(h1.y, 1);
    float iw6 = 1.0f / (float)max(h1.z, 1);
    float iw7 = 1.0f / (float)max(h1.w, 1);

    const unsigned* y32 = (const unsigned*)y;
    float a0 = 0.f, a1 = 0.f;

    for (int blk = beg; blk < end; blk += 64) {
        int m = end - blk; if (m > 64) m = 64;
        int   rv = 0;
        float wv = 0.f;
        if (lane < m) {
            int pv  = perm[blk + lane];
            int rel = pv & 7;
            rv = pv + (pv >> 3);                  // = src*9 + rel
            float wa = (rel & 1) ? iw1 : iw0;
            float wb = (rel & 1) ? iw3 : iw2;
            float wc = (rel & 1) ? iw5 : iw4;
            float wd = (rel & 1) ? iw7 : iw6;
            float we_ = (rel & 2) ? wb : wa;
            float wf  = (rel & 2) ? wd : wc;
            wv = (rel & 4) ? wf : we_;
        }

        int j = 0;
#define EDGE_LOAD(K) \
            int   p##K = __shfl(rv, j + K);                     \
            float w##K = __shfl(wv, j + K);                     \
            unsigned u##K = y32[(size_t)p##K * 64 + lane];
#define EDGE_ACC(K) \
            a0 += w##K * lof(u##K); a1 += w##K * hif(u##K);

        for (; j + 16 <= m; j += 16) {
            EDGE_LOAD(0) EDGE_LOAD(1) EDGE_LOAD(2)  EDGE_LOAD(3)
            EDGE_LOAD(4) EDGE_LOAD(5) EDGE_LOAD(6)  EDGE_LOAD(7)
            EDGE_LOAD(8) EDGE_LOAD(9) EDGE_LOAD(10) EDGE_LOAD(11)
            EDGE_LOAD(12) EDGE_LOAD(13) EDGE_LOAD(14) EDGE_LOAD(15)
            EDGE_ACC(0)  EDGE_ACC(1)  EDGE_ACC(2)  EDGE_ACC(3)
            EDGE_ACC(4)  EDGE_ACC(5)  EDGE_ACC(6)  EDGE_ACC(7)
            EDGE_ACC(8)  EDGE_ACC(9)  EDGE_ACC(10) EDGE_ACC(11)
            EDGE_ACC(12) EDGE_ACC(13) EDGE_ACC(14) EDGE_ACC(15)
        }
        if (j + 8 <= m) {
            EDGE_LOAD(0) EDGE_LOAD(1) EDGE_LOAD(2) EDGE_LOAD(3)
            EDGE_LOAD(4) EDGE_LOAD(5) EDGE_LOAD(6) EDGE_LOAD(7)
            EDGE_ACC(0) EDGE_ACC(1) EDGE_ACC(2) EDGE_ACC(3)
            EDGE_ACC(4) EDGE_ACC(5) EDGE_ACC(6) EDGE_ACC(7)
            j += 8;
        }
        if (j + 4 <= m) {
            EDGE_LOAD(0) EDGE_LOAD(1) EDGE_LOAD(2) EDGE_LOAD(3)
            EDGE_ACC(0) EDGE_ACC(1) EDGE_ACC(2) EDGE_ACC(3)
            j += 4;
        }
        for (; j < m; ++j) {
            EDGE_LOAD(0)
            EDGE_ACC(0)
        }
#undef EDGE_LOAD
#undef EDGE_ACC
    }

    // root + bias + relu
    unsigned ur = y32[(size_t)n * YWD + (NREL * CH / 2) + lane];
    float o0 = a0 + lof(ur) + bias[lane * 2];
    float o1 = a1 + hif(ur) + bias[lane * 2 + 1];
    float2 ov;
    ov.x = fmaxf(o0, 0.f);
    ov.y = fmaxf(o1, 0.f);
    *(float2*)(out + (size_t)n * CH + lane * 2) = ov;
}

extern "C" void kernel_launch(void* const* d_in, const int* in_sizes, int n_in,
                              void* d_out, int out_size, void* d_ws, size_t ws_size,
                              hipStream_t stream)
{
    const float* x    = (const float*)d_in[0];
    const int*   ei   = (const int*)d_in[1];
    const int*   et   = (const int*)d_in[2];
    const float* W    = (const float*)d_in[3];
    const float* root = (const float*)d_in[4];
    const float* bias = (const float*)d_in[5];
    float*       out  = (float*)d_out;

    int N = in_sizes[0] / CH;
    int E = in_sizes[2];
    const int* src = ei;
    const int* dst = ei + E;

    int S  = N * NREL;
    int NB = (S + SCAN_CHUNK - 1) / SCAN_CHUNK;

    // workspace layout (~250 MB — proven budget)
    unsigned short* y   = (unsigned short*)d_ws;              // N*1152 bf16
    unsigned short* Bt2 = y + (size_t)N * YW;                 // 1152*128 bf16
    int* hist     = (int*)(Bt2 + (size_t)YW * CH);            // S (persists)
    int* pad_offs = hist + S;                                 // S+1 (read-only post-finalize)
    int* partials = pad_offs + S + 1;                         // 256
    int* perm     = partials + 256;                           // E
    int* rank     = perm + E;                                 // E

    hipMemsetAsync(hist, 0, (size_t)S * sizeof(int), stream);

    int egrid = (E + 255) / 256;
    int G     = (N + 127) / 128;                              // ygemm grid
    int epb   = ((E + G - 1) / G + 2047) & ~2047;             // edges per block

    bt2_kernel<<<(YW * CH + 255) / 256, 256, 0, stream>>>(W, root, Bt2);
    hist_rank_kernel<<<egrid, 256, 0, stream>>>(dst, et, hist, rank, E);
    scan1_kernel<<<NB, SCAN_THREADS, 0, stream>>>(hist, pad_offs, partials, S);
    scan2_kernel<<<1, SCAN_THREADS, 0, stream>>>(partials, NB);
    finalize_kernel<<<(S + 256) / 256, 256, 0, stream>>>(pad_offs, partials, S, E);
    ygemm_fill_kernel<<<G, 512, 0, stream>>>(x, Bt2, y, N,
                                             src, dst, et, rank, pad_offs,
                                             perm, E, epb);
    gather_kernel<<<(N + 3) / 4, 256, 0, stream>>>(y, perm, pad_offs, hist, bias, out, N);
}

// Round 18
// 282.576 us; speedup vs baseline: 1.1225x; 1.1225x over previous
//
#include <hip/hip_runtime.h>

#define NREL 8
#define CH   128                 // IN_CH == HID == 128
#define YW   1152                // y row width: 8 rels + root, each 128
#define YWD  (YW / 2)            // y row width in dwords (576)
#define NCB2 18                  // 64-col chunks in ygemm

#define SCAN_ITEMS   16
#define SCAN_THREADS 256
#define SCAN_CHUNK   (SCAN_ITEMS * SCAN_THREADS)   // 4096
#define SCAN_SHIFT   12

typedef short  short8v __attribute__((ext_vector_type(8)));
typedef float  f32x4   __attribute__((ext_vector_type(4)));

__device__ __forceinline__ unsigned short f2bf(float f) {
    union { float f; unsigned u; } v; v.f = f;
    return (unsigned short)((v.u + 0x7FFFu + ((v.u >> 16) & 1u)) >> 16);
}
__device__ __forceinline__ float lof(unsigned u) {
    union { unsigned u; float f; } v; v.u = u << 16; return v.f;
}
__device__ __forceinline__ float hif(unsigned u) {
    union { unsigned u; float f; } v; v.u = u & 0xFFFF0000u; return v.f;
}
__device__ __forceinline__ void gload_lds16(const void* g, void* l) {
    __builtin_amdgcn_global_load_lds(
        (const __attribute__((address_space(1))) unsigned int*)g,
        (__attribute__((address_space(3))) unsigned int*)l, 16, 0, 0);
}

// ---------------------------------------------------------------------------
// 0. Bt2[rc][k] = bf16( Wcat[k][rc] ); rc = r*128+c
// ---------------------------------------------------------------------------
__global__ __launch_bounds__(256) void bt2_kernel(
    const float* __restrict__ W, const float* __restrict__ root,
    unsigned short* __restrict__ Bt2)
{
    int idx = blockIdx.x * blockDim.x + threadIdx.x;   // rc*128 + k
    if (idx >= YW * CH) return;
    int rc = idx >> 7, k = idx & 127;
    int r = rc >> 7, c = rc & 127;
    float v = (r < NREL) ? W[(size_t)(r * CH + k) * CH + c]
                         : root[(size_t)k * CH + c];
    Bt2[idx] = f2bf(v);
}

// ---------------------------------------------------------------------------
// 1. hist + rank: rank[e] = old count of segment (dst*8+et), coalesced write.
// ---------------------------------------------------------------------------
__global__ __launch_bounds__(256) void hist_rank_kernel(
    const int* __restrict__ dst, const int* __restrict__ et,
    int* __restrict__ hist, int* __restrict__ rank, int E)
{
    int e = blockIdx.x * blockDim.x + threadIdx.x;
    if (e < E) rank[e] = atomicAdd(&hist[dst[e] * NREL + et[e]], 1);
}

// ---------------------------------------------------------------------------
// 2a/2b. two-level exclusive scan over S segments -> pad_offs[i] = seg start
// ---------------------------------------------------------------------------
__global__ __launch_bounds__(SCAN_THREADS) void scan1_kernel(
    const int* __restrict__ hist, int* __restrict__ pad_offs,
    int* __restrict__ partials, int S)
{
    __shared__ int lds[SCAN_THREADS];
    int t = threadIdx.x;
    int base = blockIdx.x * SCAN_CHUNK + t * SCAN_ITEMS;
    int v[SCAN_ITEMS];
    int s = 0;
#pragma unroll
    for (int j = 0; j < SCAN_ITEMS; j++) {
        int idx = base + j;
        int h = (idx < S) ? hist[idx] : 0;
        v[j] = s; s += h;
    }
    int run = s;
    lds[t] = run; __syncthreads();
    for (int off = 1; off < SCAN_THREADS; off <<= 1) {
        int y = (t >= off) ? lds[t - off] : 0;
        __syncthreads();
        run += y; lds[t] = run; __syncthreads();
    }
    int tb = run - s;
    if (t == SCAN_THREADS - 1) partials[blockIdx.x] = run;
#pragma unroll
    for (int j = 0; j < SCAN_ITEMS; j++) {
        int idx = base + j;
        if (idx < S) pad_offs[idx] = tb + v[j];
    }
}

__global__ __launch_bounds__(SCAN_THREADS) void scan2_kernel(
    int* __restrict__ partials, int NB)
{
    __shared__ int lds[SCAN_THREADS];
    int t = threadIdx.x;
    int s = (t < NB) ? partials[t] : 0;
    int run = s;
    lds[t] = run; __syncthreads();
    for (int off = 1; off < SCAN_THREADS; off <<= 1) {
        int y = (t >= off) ? lds[t - off] : 0;
        __syncthreads();
        run += y; lds[t] = run; __syncthreads();
    }
    if (t < NB) partials[t] = run - s;
}

// ---------------------------------------------------------------------------
// 2c. pad_offs -> absolute; sentinel pad_offs[S] = E
// ---------------------------------------------------------------------------
__global__ __launch_bounds__(256) void finalize_kernel(
    int* __restrict__ pad_offs, const int* __restrict__ partials, int S, int E)
{
    int i = blockIdx.x * blockDim.x + threadIdx.x;
    if (i < S)       pad_offs[i] += partials[i >> SCAN_SHIFT];
    else if (i == S) pad_offs[i] = E;
}

// ---------------------------------------------------------------------------
// 4. FUSED ygemm + scatter-only fill (R11 — proven best, 120 µs).
//    Rank-based atomic-free fill; perm scatters spread across cb=1..4 right
//    after the barrier so each drains under a full MFMA phase; single-buffer
//    Bs (48 KB LDS total, ~44% occupancy).
// ---------------------------------------------------------------------------
__global__ __launch_bounds__(512, 6) void ygemm_fill_kernel(
    const float* __restrict__ x,
    const unsigned short* __restrict__ Bt2,   // [1152][128]
    unsigned short* __restrict__ y,           // [N][1152]
    int N,
    const int* __restrict__ src, const int* __restrict__ dst,
    const int* __restrict__ et, const int* __restrict__ rank,
    const int* __restrict__ pad_offs,
    int* __restrict__ perm, int E, int epb)
{
    __shared__ __align__(16) unsigned short As[128 * 128];  // 32 KB
    __shared__ __align__(16) unsigned short Bs[64 * 128];   // 16 KB

    int tid  = threadIdx.x;
    int lane = tid & 63;
    int wid  = tid >> 6;
    int wm   = wid >> 2;       // 0..1 -> 64-row half
    int wn   = wid & 3;        // 0..3 -> 16-col slice
    int r15  = lane & 15;
    int kg   = lane >> 4;      // 0..3
    int n0   = blockIdx.x * 128;

    // ---- fill prologue: compute positions (no atomics) ----
    int eb   = blockIdx.x * epb;
    int elim = eb + epb; if (elim > E) elim = E;
    int p0 = -1, p1 = -1, p2 = -1, p3 = -1;
    int v0 = 0, v1 = 0, v2 = 0, v3 = 0;
    {
        int e0 = eb + tid;
        int e1 = e0 + 512, e2 = e1 + 512, e3 = e2 + 512;
        if (e0 < elim) { int t0 = et[e0]; v0 = (src[e0] << 3) | t0;
                         p0 = pad_offs[dst[e0] * NREL + t0] + rank[e0]; }
        if (e1 < elim) { int t1 = et[e1]; v1 = (src[e1] << 3) | t1;
                         p1 = pad_offs[dst[e1] * NREL + t1] + rank[e1]; }
        if (e2 < elim) { int t2 = et[e2]; v2 = (src[e2] << 3) | t2;
                         p2 = pad_offs[dst[e2] * NREL + t2] + rank[e2]; }
        if (e3 < elim) { int t3 = et[e3]; v3 = (src[e3] << 3) | t3;
                         p3 = pad_offs[dst[e3] * NREL + t3] + rank[e3]; }
    }

    // ---- stage A once ----
    {
        int row = tid >> 2;
        int kq  = tid & 3;
        int gn  = n0 + row; if (gn >= N) gn = N - 1;
        const float* xp = x + (size_t)gn * CH + kq * 32;
#pragma unroll
        for (int s8 = 0; s8 < 4; ++s8) {
            float4 f0 = *(const float4*)(xp + s8 * 8);
            float4 f1 = *(const float4*)(xp + s8 * 8 + 4);
            uint4 v;
            v.x = f2bf(f0.x) | ((unsigned)f2bf(f0.y) << 16);
            v.y = f2bf(f0.z) | ((unsigned)f2bf(f0.w) << 16);
            v.z = f2bf(f1.x) | ((unsigned)f2bf(f1.y) << 16);
            v.w = f2bf(f1.z) | ((unsigned)f2bf(f1.w) << 16);
            int slot = kq * 4 + s8;
            int phys = slot ^ (row & 15);
            *(uint4*)&As[row * 128 + phys * 8] = v;
        }
    }

    for (int cb = 0; cb < NCB2; ++cb) {
        // ---- stage Bs: 64 cols x 128 k (16 x 1KB chunks, 2 per wave) ----
#pragma unroll
        for (int i = 0; i < 2; ++i) {
            int chunk = wid * 2 + i;              // 0..15
            int col   = chunk * 4 + (lane >> 4);  // 0..63
            int slot  = (lane & 15) ^ (col & 15);
            const char* srcp = (const char*)(Bt2 + (size_t)(cb * 64 + col) * CH + slot * 8);
            gload_lds16(srcp, &Bs[chunk * 512]);
        }
        __syncthreads();

        // ---- spread perm scatter: one store per early iteration ----
        if      (cb == 1) { if (p0 >= 0) perm[p0] = v0; }
        else if (cb == 2) { if (p1 >= 0) perm[p1] = v1; }
        else if (cb == 3) { if (p2 >= 0) perm[p2] = v2; }
        else if (cb == 4) { if (p3 >= 0) perm[p3] = v3; }

        f32x4 acc[4];
#pragma unroll
        for (int i = 0; i < 4; i++) acc[i] = f32x4{0.f, 0.f, 0.f, 0.f};

#pragma unroll
        for (int ks = 0; ks < 4; ++ks) {
            short8v a[4], b;
#pragma unroll
            for (int mr = 0; mr < 4; ++mr) {
                int row  = wm * 64 + mr * 16 + r15;
                int phys = (ks * 4 + kg) ^ (row & 15);
                a[mr] = *(const short8v*)&As[row * 128 + phys * 8];
            }
            {
                int col  = wn * 16 + r15;
                int phys = (ks * 4 + kg) ^ (col & 15);
                b = *(const short8v*)&Bs[col * 128 + phys * 8];
            }
#pragma unroll
            for (int mr = 0; mr < 4; ++mr)
                acc[mr] = __builtin_amdgcn_mfma_f32_16x16x32_bf16(
                    a[mr], b, acc[mr], 0, 0, 0);
        }

        // ---- epilogue: C/D layout col = lane&15, row = (lane>>4)*4+reg ----
#pragma unroll
        for (int mr = 0; mr < 4; ++mr) {
#pragma unroll
            for (int reg = 0; reg < 4; ++reg) {
                int gr = n0 + wm * 64 + mr * 16 + kg * 4 + reg;
                if (gr >= N) continue;
                int gc = cb * 64 + wn * 16 + r15;
                y[(size_t)gr * YW + gc] = f2bf(acc[mr][reg]);
            }
        }
        __syncthreads();
    }
}

// ---------------------------------------------------------------------------
// 5. gather (R11 v1): out[n] = relu( sum_e w_e * y[(pv+(pv>>3))*128..]
//    + y_root + bias ). One wave per node; unroll-16 row loads.
// ---------------------------------------------------------------------------
__global__ __launch_bounds__(256) void gather_kernel(
    const unsigned short* __restrict__ y,
    const int* __restrict__ perm,
    const int* __restrict__ pad_offs,
    const int* __restrict__ hist,
    const float* __restrict__ bias,
    float* __restrict__ out, int N)
{
    int wid  = threadIdx.x >> 6;
    int lane = threadIdx.x & 63;
    int n    = blockIdx.x * 4 + wid;
    if (n >= N) return;

    int beg = pad_offs[n * NREL];
    int end = pad_offs[n * NREL + NREL];

    int4 h0 = *(const int4*)(hist + (size_t)n * NREL);
    int4 h1 = *(const int4*)(hist + (size_t)n * NREL + 4);
    float iw0 = 1.0f / (float)max(h0.x, 1);
    float iw1 = 1.0f / (float)max(h0.y, 1);
    float iw2 = 1.0f / (float)max(h0.z, 1);
    float iw3 = 1.0f / (float)max(h0.w, 1);
    float iw4 = 1.0f / (float)max(h1.x, 1);
    float iw5 = 1.0f / (float)max(h1.y, 1);
    float iw6 = 1.0f / (float)max(h1.z, 1);
    float iw7 = 1.0f / (float)max(h1.w, 1);

    const unsigned* y32 = (const unsigned*)y;
    float a0 = 0.f, a1 = 0.f;

    for (int blk = beg; blk < end; blk += 64) {
        int m = end - blk; if (m > 64) m = 64;
        int   rv = 0;
        float wv = 0.f;
        if (lane < m) {
            int pv  = perm[blk + lane];
            int rel = pv & 7;
            rv = pv + (pv >> 3);                  // = src*9 + rel
            float wa = (rel & 1) ? iw1 : iw0;
            float wb = (rel & 1) ? iw3 : iw2;
            float wc = (rel & 1) ? iw5 : iw4;
            float wd = (rel & 1) ? iw7 : iw6;
            float we_ = (rel & 2) ? wb : wa;
            float wf  = (rel & 2) ? wd : wc;
            wv = (rel & 4) ? wf : we_;
        }

        int j = 0;
#define EDGE_LOAD(K) \
            int   p##K = __shfl(rv, j + K);                     \
            float w##K = __shfl(wv, j + K);                     \
            unsigned u##K = y32[(size_t)p##K * 64 + lane];
#define EDGE_ACC(K) \
            a0 += w##K * lof(u##K); a1 += w##K * hif(u##K);

        for (; j + 16 <= m; j += 16) {
            EDGE_LOAD(0) EDGE_LOAD(1) EDGE_LOAD(2)  EDGE_LOAD(3)
            EDGE_LOAD(4) EDGE_LOAD(5) EDGE_LOAD(6)  EDGE_LOAD(7)
            EDGE_LOAD(8) EDGE_LOAD(9) EDGE_LOAD(10) EDGE_LOAD(11)
            EDGE_LOAD(12) EDGE_LOAD(13) EDGE_LOAD(14) EDGE_LOAD(15)
            EDGE_ACC(0)  EDGE_ACC(1)  EDGE_ACC(2)  EDGE_ACC(3)
            EDGE_ACC(4)  EDGE_ACC(5)  EDGE_ACC(6)  EDGE_ACC(7)
            EDGE_ACC(8)  EDGE_ACC(9)  EDGE_ACC(10) EDGE_ACC(11)
            EDGE_ACC(12) EDGE_ACC(13) EDGE_ACC(14) EDGE_ACC(15)
        }
        if (j + 8 <= m) {
            EDGE_LOAD(0) EDGE_LOAD(1) EDGE_LOAD(2) EDGE_LOAD(3)
            EDGE_LOAD(4) EDGE_LOAD(5) EDGE_LOAD(6) EDGE_LOAD(7)
            EDGE_ACC(0) EDGE_ACC(1) EDGE_ACC(2) EDGE_ACC(3)
            EDGE_ACC(4) EDGE_ACC(5) EDGE_ACC(6) EDGE_ACC(7)
            j += 8;
        }
        if (j + 4 <= m) {
            EDGE_LOAD(0) EDGE_LOAD(1) EDGE_LOAD(2) EDGE_LOAD(3)
            EDGE_ACC(0) EDGE_ACC(1) EDGE_ACC(2) EDGE_ACC(3)
            j += 4;
        }
        for (; j < m; ++j) {
            EDGE_LOAD(0)
            EDGE_ACC(0)
        }
#undef EDGE_LOAD
#undef EDGE_ACC
    }

    // root + bias + relu
    unsigned ur = y32[(size_t)n * YWD + (NREL * CH / 2) + lane];
    float o0 = a0 + lof(ur) + bias[lane * 2];
    float o1 = a1 + hif(ur) + bias[lane * 2 + 1];
    float2 ov;
    ov.x = fmaxf(o0, 0.f);
    ov.y = fmaxf(o1, 0.f);
    *(float2*)(out + (size_t)n * CH + lane * 2) = ov;
}

extern "C" void kernel_launch(void* const* d_in, const int* in_sizes, int n_in,
                              void* d_out, int out_size, void* d_ws, size_t ws_size,
                              hipStream_t stream)
{
    const float* x    = (const float*)d_in[0];
    const int*   ei   = (const int*)d_in[1];
    const int*   et   = (const int*)d_in[2];
    const float* W    = (const float*)d_in[3];
    const float* root = (const float*)d_in[4];
    const float* bias = (const float*)d_in[5];
    float*       out  = (float*)d_out;

    int N = in_sizes[0] / CH;
    int E = in_sizes[2];
    const int* src = ei;
    const int* dst = ei + E;

    int S  = N * NREL;
    int NB = (S + SCAN_CHUNK - 1) / SCAN_CHUNK;

    // workspace layout (~250 MB — proven budget)
    unsigned short* y   = (unsigned short*)d_ws;              // N*1152 bf16
    unsigned short* Bt2 = y + (size_t)N * YW;                 // 1152*128 bf16
    int* hist     = (int*)(Bt2 + (size_t)YW * CH);            // S (persists)
    int* pad_offs = hist + S;                                 // S+1 (read-only post-finalize)
    int* partials = pad_offs + S + 1;                         // 256
    int* perm     = partials + 256;                           // E
    int* rank     = perm + E;                                 // E

    hipMemsetAsync(hist, 0, (size_t)S * sizeof(int), stream);

    int egrid = (E + 255) / 256;
    int G     = (N + 127) / 128;                              // ygemm grid
    int epb   = ((E + G - 1) / G + 2047) & ~2047;             // edges per block

    bt2_kernel<<<(YW * CH + 255) / 256, 256, 0, stream>>>(W, root, Bt2);
    hist_rank_kernel<<<egrid, 256, 0, stream>>>(dst, et, hist, rank, E);
    scan1_kernel<<<NB, SCAN_THREADS, 0, stream>>>(hist, pad_offs, partials, S);
    scan2_kernel<<<1, SCAN_THREADS, 0, stream>>>(partials, NB);
    finalize_kernel<<<(S + 256) / 256, 256, 0, stream>>>(pad_offs, partials, S, E);
    ygemm_fill_kernel<<<G, 512, 0, stream>>>(x, Bt2, y, N,
                                             src, dst, et, rank, pad_offs,
                                             perm, E, epb);
    gather_kernel<<<(N + 3) / 4, 256, 0, stream>>>(y, perm, pad_offs, hist, bias, out, N);
}

// Round 19
// 279.812 us; speedup vs baseline: 1.1335x; 1.0099x over previous
//
#include <hip/hip_runtime.h>

#define NREL 8
#define CH   128                 // IN_CH == HID == 128
#define YW   1152                // y row width: 8 rels + root, each 128
#define YWD  (YW / 2)            // y row width in dwords (576)
#define NCB2 18                  // 64-col chunks in ygemm
#define BTN  (YW * CH)           // Bt2 element count (147456)

#define SCAN_ITEMS   16
#define SCAN_THREADS 256
#define SCAN_CHUNK   (SCAN_ITEMS * SCAN_THREADS)   // 4096
#define SCAN_SHIFT   12

typedef short  short8v __attribute__((ext_vector_type(8)));
typedef float  f32x4   __attribute__((ext_vector_type(4)));

__device__ __forceinline__ unsigned short f2bf(float f) {
    union { float f; unsigned u; } v; v.f = f;
    return (unsigned short)((v.u + 0x7FFFu + ((v.u >> 16) & 1u)) >> 16);
}
__device__ __forceinline__ float lof(unsigned u) {
    union { unsigned u; float f; } v; v.u = u << 16; return v.f;
}
__device__ __forceinline__ float hif(unsigned u) {
    union { unsigned u; float f; } v; v.u = u & 0xFFFF0000u; return v.f;
}
__device__ __forceinline__ void gload_lds16(const void* g, void* l) {
    __builtin_amdgcn_global_load_lds(
        (const __attribute__((address_space(1))) unsigned int*)g,
        (__attribute__((address_space(3))) unsigned int*)l, 16, 0, 0);
}

// ---------------------------------------------------------------------------
// 1. FUSED hist+rank (+Bt2 build). rank[e] = old count of seg (dst*8+et),
//    coalesced write. First 147456 threads also build Bt2 (independent).
// ---------------------------------------------------------------------------
__global__ __launch_bounds__(256) void hist_rank_bt2_kernel(
    const int* __restrict__ dst, const int* __restrict__ et,
    int* __restrict__ hist, int* __restrict__ rank, int E,
    const float* __restrict__ W, const float* __restrict__ root,
    unsigned short* __restrict__ Bt2)
{
    int e = blockIdx.x * blockDim.x + threadIdx.x;
    if (e < E) rank[e] = atomicAdd(&hist[dst[e] * NREL + et[e]], 1);
    if (e < BTN) {
        int rc = e >> 7, k = e & 127;
        int r = rc >> 7, c = rc & 127;
        float v = (r < NREL) ? W[(size_t)(r * CH + k) * CH + c]
                             : root[(size_t)k * CH + c];
        Bt2[e] = f2bf(v);
    }
}

// ---------------------------------------------------------------------------
// 2a. per-chunk exclusive scan over S segments -> pad_offs (chunk-local)
// ---------------------------------------------------------------------------
__global__ __launch_bounds__(SCAN_THREADS) void scan1_kernel(
    const int* __restrict__ hist, int* __restrict__ pad_offs,
    int* __restrict__ partials, int S)
{
    __shared__ int lds[SCAN_THREADS];
    int t = threadIdx.x;
    int base = blockIdx.x * SCAN_CHUNK + t * SCAN_ITEMS;
    int v[SCAN_ITEMS];
    int s = 0;
#pragma unroll
    for (int j = 0; j < SCAN_ITEMS; j++) {
        int idx = base + j;
        int h = (idx < S) ? hist[idx] : 0;
        v[j] = s; s += h;
    }
    int run = s;
    lds[t] = run; __syncthreads();
    for (int off = 1; off < SCAN_THREADS; off <<= 1) {
        int y = (t >= off) ? lds[t - off] : 0;
        __syncthreads();
        run += y; lds[t] = run; __syncthreads();
    }
    int tb = run - s;
    if (t == SCAN_THREADS - 1) partials[blockIdx.x] = run;
#pragma unroll
    for (int j = 0; j < SCAN_ITEMS; j++) {
        int idx = base + j;
        if (idx < S) pad_offs[idx] = tb + v[j];
    }
}

// ---------------------------------------------------------------------------
// 2b. single-block exclusive scan of chunk totals; write sentinel
//     pad_offs[S] = E (consumers add partials on the fly; no finalize pass).
// ---------------------------------------------------------------------------
__global__ __launch_bounds__(SCAN_THREADS) void scan2_kernel(
    int* __restrict__ partials, int NB, int* __restrict__ pad_offs,
    int S, int E)
{
    __shared__ int lds[SCAN_THREADS];
    int t = threadIdx.x;
    int s = (t < NB) ? partials[t] : 0;
    int run = s;
    lds[t] = run; __syncthreads();
    for (int off = 1; off < SCAN_THREADS; off <<= 1) {
        int y = (t >= off) ? lds[t - off] : 0;
        __syncthreads();
        run += y; lds[t] = run; __syncthreads();
    }
    if (t < NB) partials[t] = run - s;
    if (t == 0) pad_offs[S] = E;
}

// ---------------------------------------------------------------------------
// 4. FUSED ygemm + scatter-only fill (R11 — proven best).
//    pos = pad_offs[seg] + partials[seg>>12] + rank[e]; perm scatters spread
//    across cb=1..4 right after the barrier; single-buffer Bs (48 KB LDS).
// ---------------------------------------------------------------------------
__global__ __launch_bounds__(512, 6) void ygemm_fill_kernel(
    const float* __restrict__ x,
    const unsigned short* __restrict__ Bt2,   // [1152][128]
    unsigned short* __restrict__ y,           // [N][1152]
    int N,
    const int* __restrict__ src, const int* __restrict__ dst,
    const int* __restrict__ et, const int* __restrict__ rank,
    const int* __restrict__ pad_offs, const int* __restrict__ partials,
    int* __restrict__ perm, int E, int epb)
{
    __shared__ __align__(16) unsigned short As[128 * 128];  // 32 KB
    __shared__ __align__(16) unsigned short Bs[64 * 128];   // 16 KB

    int tid  = threadIdx.x;
    int lane = tid & 63;
    int wid  = tid >> 6;
    int wm   = wid >> 2;       // 0..1 -> 64-row half
    int wn   = wid & 3;        // 0..3 -> 16-col slice
    int r15  = lane & 15;
    int kg   = lane >> 4;      // 0..3
    int n0   = blockIdx.x * 128;

    // ---- fill prologue: compute positions (no atomics) ----
    int eb   = blockIdx.x * epb;
    int elim = eb + epb; if (elim > E) elim = E;
    int p0 = -1, p1 = -1, p2 = -1, p3 = -1;
    int v0 = 0, v1 = 0, v2 = 0, v3 = 0;
    {
        int e0 = eb + tid;
        int e1 = e0 + 512, e2 = e1 + 512, e3 = e2 + 512;
        if (e0 < elim) { int t0 = et[e0]; v0 = (src[e0] << 3) | t0;
                         int sg = dst[e0] * NREL + t0;
                         p0 = pad_offs[sg] + partials[sg >> SCAN_SHIFT] + rank[e0]; }
        if (e1 < elim) { int t1 = et[e1]; v1 = (src[e1] << 3) | t1;
                         int sg = dst[e1] * NREL + t1;
                         p1 = pad_offs[sg] + partials[sg >> SCAN_SHIFT] + rank[e1]; }
        if (e2 < elim) { int t2 = et[e2]; v2 = (src[e2] << 3) | t2;
                         int sg = dst[e2] * NREL + t2;
                         p2 = pad_offs[sg] + partials[sg >> SCAN_SHIFT] + rank[e2]; }
        if (e3 < elim) { int t3 = et[e3]; v3 = (src[e3] << 3) | t3;
                         int sg = dst[e3] * NREL + t3;
                         p3 = pad_offs[sg] + partials[sg >> SCAN_SHIFT] + rank[e3]; }
    }

    // ---- stage A once ----
    {
        int row = tid >> 2;
        int kq  = tid & 3;
        int gn  = n0 + row; if (gn >= N) gn = N - 1;
        const float* xp = x + (size_t)gn * CH + kq * 32;
#pragma unroll
        for (int s8 = 0; s8 < 4; ++s8) {
            float4 f0 = *(const float4*)(xp + s8 * 8);
            float4 f1 = *(const float4*)(xp + s8 * 8 + 4);
            uint4 v;
            v.x = f2bf(f0.x) | ((unsigned)f2bf(f0.y) << 16);
            v.y = f2bf(f0.z) | ((unsigned)f2bf(f0.w) << 16);
            v.z = f2bf(f1.x) | ((unsigned)f2bf(f1.y) << 16);
            v.w = f2bf(f1.z) | ((unsigned)f2bf(f1.w) << 16);
            int slot = kq * 4 + s8;
            int phys = slot ^ (row & 15);
            *(uint4*)&As[row * 128 + phys * 8] = v;
        }
    }

    for (int cb = 0; cb < NCB2; ++cb) {
        // ---- stage Bs: 64 cols x 128 k (16 x 1KB chunks, 2 per wave) ----
#pragma unroll
        for (int i = 0; i < 2; ++i) {
            int chunk = wid * 2 + i;              // 0..15
            int col   = chunk * 4 + (lane >> 4);  // 0..63
            int slot  = (lane & 15) ^ (col & 15);
            const char* srcp = (const char*)(Bt2 + (size_t)(cb * 64 + col) * CH + slot * 8);
            gload_lds16(srcp, &Bs[chunk * 512]);
        }
        __syncthreads();

        // ---- spread perm scatter: one store per early iteration ----
        if      (cb == 1) { if (p0 >= 0) perm[p0] = v0; }
        else if (cb == 2) { if (p1 >= 0) perm[p1] = v1; }
        else if (cb == 3) { if (p2 >= 0) perm[p2] = v2; }
        else if (cb == 4) { if (p3 >= 0) perm[p3] = v3; }

        f32x4 acc[4];
#pragma unroll
        for (int i = 0; i < 4; i++) acc[i] = f32x4{0.f, 0.f, 0.f, 0.f};

#pragma unroll
        for (int ks = 0; ks < 4; ++ks) {
            short8v a[4], b;
#pragma unroll
            for (int mr = 0; mr < 4; ++mr) {
                int row  = wm * 64 + mr * 16 + r15;
                int phys = (ks * 4 + kg) ^ (row & 15);
                a[mr] = *(const short8v*)&As[row * 128 + phys * 8];
            }
            {
                int col  = wn * 16 + r15;
                int phys = (ks * 4 + kg) ^ (col & 15);
                b = *(const short8v*)&Bs[col * 128 + phys * 8];
            }
#pragma unroll
            for (int mr = 0; mr < 4; ++mr)
                acc[mr] = __builtin_amdgcn_mfma_f32_16x16x32_bf16(
                    a[mr], b, acc[mr], 0, 0, 0);
        }

        // ---- epilogue: C/D layout col = lane&15, row = (lane>>4)*4+reg ----
#pragma unroll
        for (int mr = 0; mr < 4; ++mr) {
#pragma unroll
            for (int reg = 0; reg < 4; ++reg) {
                int gr = n0 + wm * 64 + mr * 16 + kg * 4 + reg;
                if (gr >= N) continue;
                int gc = cb * 64 + wn * 16 + r15;
                y[(size_t)gr * YW + gc] = f2bf(acc[mr][reg]);
            }
        }
        __syncthreads();
    }
}

// ---------------------------------------------------------------------------
// 5. gather (R11 v1): out[n] = relu( sum_e w_e * y[(pv+(pv>>3))*128..]
//    + y_root + bias ). Boundaries = pad_offs + partials on the fly.
// ---------------------------------------------------------------------------
__global__ __launch_bounds__(256) void gather_kernel(
    const unsigned short* __restrict__ y,
    const int* __restrict__ perm,
    const int* __restrict__ pad_offs,
    const int* __restrict__ partials,
    const int* __restrict__ hist,
    const float* __restrict__ bias,
    float* __restrict__ out, int N)
{
    int wid  = threadIdx.x >> 6;
    int lane = threadIdx.x & 63;
    int n    = blockIdx.x * 4 + wid;
    if (n >= N) return;

    int S  = N * NREL;
    int i0 = n * NREL;
    int i8 = i0 + NREL;
    int beg = pad_offs[i0] + partials[i0 >> SCAN_SHIFT];
    int end = pad_offs[i8] + ((i8 == S) ? 0 : partials[i8 >> SCAN_SHIFT]);

    int4 h0 = *(const int4*)(hist + (size_t)n * NREL);
    int4 h1 = *(const int4*)(hist + (size_t)n * NREL + 4);
    float iw0 = 1.0f / (float)max(h0.x, 1);
    float iw1 = 1.0f / (float)max(h0.y, 1);
    float iw2 = 1.0f / (float)max(h0.z, 1);
    float iw3 = 1.0f / (float)max(h0.w, 1);
    float iw4 = 1.0f / (float)max(h1.x, 1);
    float iw5 = 1.0f / (float)max(h1.y, 1);
    float iw6 = 1.0f / (float)max(h1.z, 1);
    float iw7 = 1.0f / (float)max(h1.w, 1);

    const unsigned* y32 = (const unsigned*)y;
    float a0 = 0.f, a1 = 0.f;

    for (int blk = beg; blk < end; blk += 64) {
        int m = end - blk; if (m > 64) m = 64;
        int   rv = 0;
        float wv = 0.f;
        if (lane < m) {
            int pv  = perm[blk + lane];
            int rel = pv & 7;
            rv = pv + (pv >> 3);                  // = src*9 + rel
            float wa = (rel & 1) ? iw1 : iw0;
            float wb = (rel & 1) ? iw3 : iw2;
            float wc = (rel & 1) ? iw5 : iw4;
            float wd = (rel & 1) ? iw7 : iw6;
            float we_ = (rel & 2) ? wb : wa;
            float wf  = (rel & 2) ? wd : wc;
            wv = (rel & 4) ? wf : we_;
        }

        int j = 0;
#define EDGE_LOAD(K) \
            int   p##K = __shfl(rv, j + K);                     \
            float w##K = __shfl(wv, j + K);                     \
            unsigned u##K = y32[(size_t)p##K * 64 + lane];
#define EDGE_ACC(K) \
            a0 += w##K * lof(u##K); a1 += w##K * hif(u##K);

        for (; j + 16 <= m; j += 16) {
            EDGE_LOAD(0) EDGE_LOAD(1) EDGE_LOAD(2)  EDGE_LOAD(3)
            EDGE_LOAD(4) EDGE_LOAD(5) EDGE_LOAD(6)  EDGE_LOAD(7)
            EDGE_LOAD(8) EDGE_LOAD(9) EDGE_LOAD(10) EDGE_LOAD(11)
            EDGE_LOAD(12) EDGE_LOAD(13) EDGE_LOAD(14) EDGE_LOAD(15)
            EDGE_ACC(0)  EDGE_ACC(1)  EDGE_ACC(2)  EDGE_ACC(3)
            EDGE_ACC(4)  EDGE_ACC(5)  EDGE_ACC(6)  EDGE_ACC(7)
            EDGE_ACC(8)  EDGE_ACC(9)  EDGE_ACC(10) EDGE_ACC(11)
            EDGE_ACC(12) EDGE_ACC(13) EDGE_ACC(14) EDGE_ACC(15)
        }
        if (j + 8 <= m) {
            EDGE_LOAD(0) EDGE_LOAD(1) EDGE_LOAD(2) EDGE_LOAD(3)
            EDGE_LOAD(4) EDGE_LOAD(5) EDGE_LOAD(6) EDGE_LOAD(7)
            EDGE_ACC(0) EDGE_ACC(1) EDGE_ACC(2) EDGE_ACC(3)
            EDGE_ACC(4) EDGE_ACC(5) EDGE_ACC(6) EDGE_ACC(7)
            j += 8;
        }
        if (j + 4 <= m) {
            EDGE_LOAD(0) EDGE_LOAD(1) EDGE_LOAD(2) EDGE_LOAD(3)
            EDGE_ACC(0) EDGE_ACC(1) EDGE_ACC(2) EDGE_ACC(3)
            j += 4;
        }
        for (; j < m; ++j) {
            EDGE_LOAD(0)
            EDGE_ACC(0)
        }
#undef EDGE_LOAD
#undef EDGE_ACC
    }

    // root + bias + relu
    unsigned ur = y32[(size_t)n * YWD + (NREL * CH / 2) + lane];
    float o0 = a0 + lof(ur) + bias[lane * 2];
    float o1 = a1 + hif(ur) + bias[lane * 2 + 1];
    float2 ov;
    ov.x = fmaxf(o0, 0.f);
    ov.y = fmaxf(o1, 0.f);
    *(float2*)(out + (size_t)n * CH + lane * 2) = ov;
}

extern "C" void kernel_launch(void* const* d_in, const int* in_sizes, int n_in,
                              void* d_out, int out_size, void* d_ws, size_t ws_size,
                              hipStream_t stream)
{
    const float* x    = (const float*)d_in[0];
    const int*   ei   = (const int*)d_in[1];
    const int*   et   = (const int*)d_in[2];
    const float* W    = (const float*)d_in[3];
    const float* root = (const float*)d_in[4];
    const float* bias = (const float*)d_in[5];
    float*       out  = (float*)d_out;

    int N = in_sizes[0] / CH;
    int E = in_sizes[2];
    const int* src = ei;
    const int* dst = ei + E;

    int S  = N * NREL;
    int NB = (S + SCAN_CHUNK - 1) / SCAN_CHUNK;

    // workspace layout (~250 MB — proven budget)
    unsigned short* y   = (unsigned short*)d_ws;              // N*1152 bf16
    unsigned short* Bt2 = y + (size_t)N * YW;                 // 1152*128 bf16
    int* hist     = (int*)(Bt2 + (size_t)YW * CH);            // S
    int* pad_offs = hist + S;                                 // S+1 (chunk-local)
    int* partials = pad_offs + S + 1;                         // 256
    int* perm     = partials + 256;                           // E
    int* rank     = perm + E;                                 // E

    hipMemsetAsync(hist, 0, (size_t)S * sizeof(int), stream);

    int egrid = (E + 255) / 256;
    int G     = (N + 127) / 128;                              // ygemm grid
    int epb   = ((E + G - 1) / G + 2047) & ~2047;             // edges per block

    hist_rank_bt2_kernel<<<egrid, 256, 0, stream>>>(dst, et, hist, rank, E,
                                                    W, root, Bt2);
    scan1_kernel<<<NB, SCAN_THREADS, 0, stream>>>(hist, pad_offs, partials, S);
    scan2_kernel<<<1, SCAN_THREADS, 0, stream>>>(partials, NB, pad_offs, S, E);
    ygemm_fill_kernel<<<G, 512, 0, stream>>>(x, Bt2, y, N,
                                             src, dst, et, rank, pad_offs,
                                             partials, perm, E, epb);
    gather_kernel<<<(N + 3) / 4, 256, 0, stream>>>(y, perm, pad_offs, partials,
                                                   hist, bias, out, N);
}

// Round 20
// 264.493 us; speedup vs baseline: 1.1992x; 1.0579x over previous
//
#include <hip/hip_runtime.h>

#define NREL 8
#define CH   128                 // IN_CH == HID == 128
#define YW   1152                // y row width: 8 rels + root, each 128
#define YWD  (YW / 2)            // y row width in dwords (576)
#define NCB2 18                  // 64-col chunks in ygemm
#define BTN  (YW * CH)           // Bt2 element count (147456)
#define BM   256                 // ygemm row tile

#define SCAN_ITEMS   16
#define SCAN_THREADS 256
#define SCAN_CHUNK   (SCAN_ITEMS * SCAN_THREADS)   // 4096
#define SCAN_SHIFT   12

typedef short  short8v __attribute__((ext_vector_type(8)));
typedef float  f32x4   __attribute__((ext_vector_type(4)));

__device__ __forceinline__ unsigned short f2bf(float f) {
    union { float f; unsigned u; } v; v.f = f;
    return (unsigned short)((v.u + 0x7FFFu + ((v.u >> 16) & 1u)) >> 16);
}
__device__ __forceinline__ float lof(unsigned u) {
    union { unsigned u; float f; } v; v.u = u << 16; return v.f;
}
__device__ __forceinline__ float hif(unsigned u) {
    union { unsigned u; float f; } v; v.u = u & 0xFFFF0000u; return v.f;
}
__device__ __forceinline__ void gload_lds16(const void* g, void* l) {
    __builtin_amdgcn_global_load_lds(
        (const __attribute__((address_space(1))) unsigned int*)g,
        (__attribute__((address_space(3))) unsigned int*)l, 16, 0, 0);
}

// ---------------------------------------------------------------------------
// 1. FUSED hist+rank (+Bt2 build).
// ---------------------------------------------------------------------------
__global__ __launch_bounds__(256) void hist_rank_bt2_kernel(
    const int* __restrict__ dst, const int* __restrict__ et,
    int* __restrict__ hist, int* __restrict__ rank, int E,
    const float* __restrict__ W, const float* __restrict__ root,
    unsigned short* __restrict__ Bt2)
{
    int e = blockIdx.x * blockDim.x + threadIdx.x;
    if (e < E) rank[e] = atomicAdd(&hist[dst[e] * NREL + et[e]], 1);
    if (e < BTN) {
        int rc = e >> 7, k = e & 127;
        int r = rc >> 7, c = rc & 127;
        float v = (r < NREL) ? W[(size_t)(r * CH + k) * CH + c]
                             : root[(size_t)k * CH + c];
        Bt2[e] = f2bf(v);
    }
}

// ---------------------------------------------------------------------------
// 2a. per-chunk exclusive scan over S segments -> pad_offs (chunk-local)
// ---------------------------------------------------------------------------
__global__ __launch_bounds__(SCAN_THREADS) void scan1_kernel(
    const int* __restrict__ hist, int* __restrict__ pad_offs,
    int* __restrict__ partials, int S)
{
    __shared__ int lds[SCAN_THREADS];
    int t = threadIdx.x;
    int base = blockIdx.x * SCAN_CHUNK + t * SCAN_ITEMS;
    int v[SCAN_ITEMS];
    int s = 0;
#pragma unroll
    for (int j = 0; j < SCAN_ITEMS; j++) {
        int idx = base + j;
        int h = (idx < S) ? hist[idx] : 0;
        v[j] = s; s += h;
    }
    int run = s;
    lds[t] = run; __syncthreads();
    for (int off = 1; off < SCAN_THREADS; off <<= 1) {
        int y = (t >= off) ? lds[t - off] : 0;
        __syncthreads();
        run += y; lds[t] = run; __syncthreads();
    }
    int tb = run - s;
    if (t == SCAN_THREADS - 1) partials[blockIdx.x] = run;
#pragma unroll
    for (int j = 0; j < SCAN_ITEMS; j++) {
        int idx = base + j;
        if (idx < S) pad_offs[idx] = tb + v[j];
    }
}

// ---------------------------------------------------------------------------
// 2b. single-block exclusive scan of chunk totals; sentinel pad_offs[S] = E.
// ---------------------------------------------------------------------------
__global__ __launch_bounds__(SCAN_THREADS) void scan2_kernel(
    int* __restrict__ partials, int NB, int* __restrict__ pad_offs,
    int S, int E)
{
    __shared__ int lds[SCAN_THREADS];
    int t = threadIdx.x;
    int s = (t < NB) ? partials[t] : 0;
    int run = s;
    lds[t] = run; __syncthreads();
    for (int off = 1; off < SCAN_THREADS; off <<= 1) {
        int y = (t >= off) ? lds[t - off] : 0;
        __syncthreads();
        run += y; lds[t] = run; __syncthreads();
    }
    if (t < NB) partials[t] = run - s;
    if (t == 0) pad_offs[S] = E;
}

// ---------------------------------------------------------------------------
// 4. FUSED ygemm + scatter-only fill — BM=256 row tile (2x MFMA per barrier).
//    80 KB LDS (As 64 + Bs 16) -> 2 blocks/CU. Wave grid 4x2: each wave
//    64 rows x 32 cols per cb (32 MFMA). Fill: 8 edges/thread, scatters
//    spread across cb=1..8.
// ---------------------------------------------------------------------------
__global__ __launch_bounds__(512, 4) void ygemm_fill_kernel(
    const float* __restrict__ x,
    const unsigned short* __restrict__ Bt2,   // [1152][128]
    unsigned short* __restrict__ y,           // [N][1152]
    int N,
    const int* __restrict__ src, const int* __restrict__ dst,
    const int* __restrict__ et, const int* __restrict__ rank,
    const int* __restrict__ pad_offs, const int* __restrict__ partials,
    int* __restrict__ perm, int E, int epb)
{
    __shared__ __align__(16) unsigned short As[BM * 128];   // 64 KB
    __shared__ __align__(16) unsigned short Bs[64 * 128];   // 16 KB

    int tid  = threadIdx.x;
    int lane = tid & 63;
    int wid  = tid >> 6;
    int wm   = wid >> 1;       // 0..3 -> 64-row quarter
    int wn   = wid & 1;        // 0..1 -> 32-col half
    int r15  = lane & 15;
    int kg   = lane >> 4;      // 0..3
    int n0   = blockIdx.x * BM;

    // ---- fill prologue: 8 edges/thread, positions (no atomics) ----
    int eb   = blockIdx.x * epb;
    int elim = eb + epb; if (elim > E) elim = E;
    int pp[8], vv[8];
#pragma unroll
    for (int i = 0; i < 8; ++i) {
        int e = eb + tid + i * 512;
        pp[i] = -1; vv[i] = 0;
        if (e < elim) {
            int t0 = et[e];
            vv[i] = (src[e] << 3) | t0;
            int sg = dst[e] * NREL + t0;
            pp[i] = pad_offs[sg] + partials[sg >> SCAN_SHIFT] + rank[e];
        }
    }

    // ---- stage A once: 256 rows x 128 k; thread = (row = tid>>1, half) ----
    {
        int row  = tid >> 1;
        int half = tid & 1;
        int gn   = n0 + row; if (gn >= N) gn = N - 1;
        const float* xp = x + (size_t)gn * CH + half * 64;
#pragma unroll
        for (int s8 = 0; s8 < 8; ++s8) {
            float4 f0 = *(const float4*)(xp + s8 * 8);
            float4 f1 = *(const float4*)(xp + s8 * 8 + 4);
            uint4 v;
            v.x = f2bf(f0.x) | ((unsigned)f2bf(f0.y) << 16);
            v.y = f2bf(f0.z) | ((unsigned)f2bf(f0.w) << 16);
            v.z = f2bf(f1.x) | ((unsigned)f2bf(f1.y) << 16);
            v.w = f2bf(f1.z) | ((unsigned)f2bf(f1.w) << 16);
            int slot = half * 8 + s8;
            int phys = slot ^ (row & 15);
            *(uint4*)&As[row * 128 + phys * 8] = v;
        }
    }

    for (int cb = 0; cb < NCB2; ++cb) {
        // ---- stage Bs: 64 cols x 128 k (16 x 1KB chunks, 2 per wave) ----
#pragma unroll
        for (int i = 0; i < 2; ++i) {
            int chunk = wid * 2 + i;              // 0..15
            int col   = chunk * 4 + (lane >> 4);  // 0..63
            int slot  = (lane & 15) ^ (col & 15);
            const char* srcp = (const char*)(Bt2 + (size_t)(cb * 64 + col) * CH + slot * 8);
            gload_lds16(srcp, &Bs[chunk * 512]);
        }
        __syncthreads();

        // ---- spread perm scatter: one store per early iteration ----
        if (cb >= 1 && cb <= 8) {
            int i = cb - 1;
            if (pp[i] >= 0) perm[pp[i]] = vv[i];
        }

        f32x4 acc[4][2];
#pragma unroll
        for (int i = 0; i < 4; i++)
#pragma unroll
            for (int j = 0; j < 2; j++)
                acc[i][j] = f32x4{0.f, 0.f, 0.f, 0.f};

#pragma unroll
        for (int ks = 0; ks < 4; ++ks) {
            short8v a[4], b[2];
#pragma unroll
            for (int mr = 0; mr < 4; ++mr) {
                int row  = wm * 64 + mr * 16 + r15;
                int phys = (ks * 4 + kg) ^ (row & 15);
                a[mr] = *(const short8v*)&As[row * 128 + phys * 8];
            }
#pragma unroll
            for (int nc = 0; nc < 2; ++nc) {
                int col  = wn * 32 + nc * 16 + r15;
                int phys = (ks * 4 + kg) ^ (col & 15);
                b[nc] = *(const short8v*)&Bs[col * 128 + phys * 8];
            }
#pragma unroll
            for (int mr = 0; mr < 4; ++mr)
#pragma unroll
                for (int nc = 0; nc < 2; ++nc)
                    acc[mr][nc] = __builtin_amdgcn_mfma_f32_16x16x32_bf16(
                        a[mr], b[nc], acc[mr][nc], 0, 0, 0);
        }

        // ---- epilogue: C/D layout col = lane&15, row = (lane>>4)*4+reg ----
#pragma unroll
        for (int mr = 0; mr < 4; ++mr) {
#pragma unroll
            for (int nc = 0; nc < 2; ++nc) {
                int gc = cb * 64 + wn * 32 + nc * 16 + r15;
#pragma unroll
                for (int reg = 0; reg < 4; ++reg) {
                    int gr = n0 + wm * 64 + mr * 16 + kg * 4 + reg;
                    if (gr >= N) continue;
                    y[(size_t)gr * YW + gc] = f2bf(acc[mr][nc][reg]);
                }
            }
        }
        __syncthreads();
    }
}

// ---------------------------------------------------------------------------
// 5. gather (R11 v1 — proven): out[n] = relu( sum_e w_e * y[...] + root + b )
// ---------------------------------------------------------------------------
__global__ __launch_bounds__(256) void gather_kernel(
    const unsigned short* __restrict__ y,
    const int* __restrict__ perm,
    const int* __restrict__ pad_offs,
    const int* __restrict__ partials,
    const int* __restrict__ hist,
    const float* __restrict__ bias,
    float* __restrict__ out, int N)
{
    int wid  = threadIdx.x >> 6;
    int lane = threadIdx.x & 63;
    int n    = blockIdx.x * 4 + wid;
    if (n >= N) return;

    int S  = N * NREL;
    int i0 = n * NREL;
    int i8 = i0 + NREL;
    int beg = pad_offs[i0] + partials[i0 >> SCAN_SHIFT];
    int end = pad_offs[i8] + ((i8 == S) ? 0 : partials[i8 >> SCAN_SHIFT]);

    int4 h0 = *(const int4*)(hist + (size_t)n * NREL);
    int4 h1 = *(const int4*)(hist + (size_t)n * NREL + 4);
    float iw0 = 1.0f / (float)max(h0.x, 1);
    float iw1 = 1.0f / (float)max(h0.y, 1);
    float iw2 = 1.0f / (float)max(h0.z, 1);
    float iw3 = 1.0f / (float)max(h0.w, 1);
    float iw4 = 1.0f / (float)max(h1.x, 1);
    float iw5 = 1.0f / (float)max(h1.y, 1);
    float iw6 = 1.0f / (float)max(h1.z, 1);
    float iw7 = 1.0f / (float)max(h1.w, 1);

    const unsigned* y32 = (const unsigned*)y;
    float a0 = 0.f, a1 = 0.f;

    for (int blk = beg; blk < end; blk += 64) {
        int m = end - blk; if (m > 64) m = 64;
        int   rv = 0;
        float wv = 0.f;
        if (lane < m) {
            int pv  = perm[blk + lane];
            int rel = pv & 7;
            rv = pv + (pv >> 3);                  // = src*9 + rel
            float wa = (rel & 1) ? iw1 : iw0;
            float wb = (rel & 1) ? iw3 : iw2;
            float wc = (rel & 1) ? iw5 : iw4;
            float wd = (rel & 1) ? iw7 : iw6;
            float we_ = (rel & 2) ? wb : wa;
            float wf  = (rel & 2) ? wd : wc;
            wv = (rel & 4) ? wf : we_;
        }

        int j = 0;
#define EDGE_LOAD(K) \
            int   p##K = __shfl(rv, j + K);                     \
            float w##K = __shfl(wv, j + K);                     \
            unsigned u##K = y32[(size_t)p##K * 64 + lane];
#define EDGE_ACC(K) \
            a0 += w##K * lof(u##K); a1 += w##K * hif(u##K);

        for (; j + 16 <= m; j += 16) {
            EDGE_LOAD(0) EDGE_LOAD(1) EDGE_LOAD(2)  EDGE_LOAD(3)
            EDGE_LOAD(4) EDGE_LOAD(5) EDGE_LOAD(6)  EDGE_LOAD(7)
            EDGE_LOAD(8) EDGE_LOAD(9) EDGE_LOAD(10) EDGE_LOAD(11)
            EDGE_LOAD(12) EDGE_LOAD(13) EDGE_LOAD(14) EDGE_LOAD(15)
            EDGE_ACC(0)  EDGE_ACC(1)  EDGE_ACC(2)  EDGE_ACC(3)
            EDGE_ACC(4)  EDGE_ACC(5)  EDGE_ACC(6)  EDGE_ACC(7)
            EDGE_ACC(8)  EDGE_ACC(9)  EDGE_ACC(10) EDGE_ACC(11)
            EDGE_ACC(12) EDGE_ACC(13) EDGE_ACC(14) EDGE_ACC(15)
        }
        if (j + 8 <= m) {
            EDGE_LOAD(0) EDGE_LOAD(1) EDGE_LOAD(2) EDGE_LOAD(3)
            EDGE_LOAD(4) EDGE_LOAD(5) EDGE_LOAD(6) EDGE_LOAD(7)
            EDGE_ACC(0) EDGE_ACC(1) EDGE_ACC(2) EDGE_ACC(3)
            EDGE_ACC(4) EDGE_ACC(5) EDGE_ACC(6) EDGE_ACC(7)
            j += 8;
        }
        if (j + 4 <= m) {
            EDGE_LOAD(0) EDGE_LOAD(1) EDGE_LOAD(2) EDGE_LOAD(3)
            EDGE_ACC(0) EDGE_ACC(1) EDGE_ACC(2) EDGE_ACC(3)
            j += 4;
        }
        for (; j < m; ++j) {
            EDGE_LOAD(0)
            EDGE_ACC(0)
        }
#undef EDGE_LOAD
#undef EDGE_ACC
    }

    // root + bias + relu
    unsigned ur = y32[(size_t)n * YWD + (NREL * CH / 2) + lane];
    float o0 = a0 + lof(ur) + bias[lane * 2];
    float o1 = a1 + hif(ur) + bias[lane * 2 + 1];
    float2 ov;
    ov.x = fmaxf(o0, 0.f);
    ov.y = fmaxf(o1, 0.f);
    *(float2*)(out + (size_t)n * CH + lane * 2) = ov;
}

extern "C" void kernel_launch(void* const* d_in, const int* in_sizes, int n_in,
                              void* d_out, int out_size, void* d_ws, size_t ws_size,
                              hipStream_t stream)
{
    const float* x    = (const float*)d_in[0];
    const int*   ei   = (const int*)d_in[1];
    const int*   et   = (const int*)d_in[2];
    const float* W    = (const float*)d_in[3];
    const float* root = (const float*)d_in[4];
    const float* bias = (const float*)d_in[5];
    float*       out  = (float*)d_out;

    int N = in_sizes[0] / CH;
    int E = in_sizes[2];
    const int* src = ei;
    const int* dst = ei + E;

    int S  = N * NREL;
    int NB = (S + SCAN_CHUNK - 1) / SCAN_CHUNK;

    // workspace layout (~250 MB — proven budget)
    unsigned short* y   = (unsigned short*)d_ws;              // N*1152 bf16
    unsigned short* Bt2 = y + (size_t)N * YW;                 // 1152*128 bf16
    int* hist     = (int*)(Bt2 + (size_t)YW * CH);            // S
    int* pad_offs = hist + S;                                 // S+1 (chunk-local)
    int* partials = pad_offs + S + 1;                         // 256
    int* perm     = partials + 256;                           // E
    int* rank     = perm + E;                                 // E

    hipMemsetAsync(hist, 0, (size_t)S * sizeof(int), stream);

    int egrid = (E + 255) / 256;
    int G     = (N + BM - 1) / BM;                            // ygemm grid
    int epb   = ((E + G - 1) / G + 4095) & ~4095;             // edges per block

    hist_rank_bt2_kernel<<<egrid, 256, 0, stream>>>(dst, et, hist, rank, E,
                                                    W, root, Bt2);
    scan1_kernel<<<NB, SCAN_THREADS, 0, stream>>>(hist, pad_offs, partials, S);
    scan2_kernel<<<1, SCAN_THREADS, 0, stream>>>(partials, NB, pad_offs, S, E);
    ygemm_fill_kernel<<<G, 512, 0, stream>>>(x, Bt2, y, N,
                                             src, dst, et, rank, pad_offs,
                                             partials, perm, E, epb);
    gather_kernel<<<(N + 3) / 4, 256, 0, stream>>>(y, perm, pad_offs, partials,
                                                   hist, bias, out, N);
}